// Round 1
// baseline (882.937 us; speedup 1.0000x reference)
//
#include <hip/hip_runtime.h>
#include <cstdint>

#define TT 16
#define NN 20000
#define CC 128
#define EE 320000
#define KKDIM 384
#define EPSV 1e-5f

typedef unsigned short u16;
typedef u16 u16x4 __attribute__((ext_vector_type(4)));
typedef u16 u16x8 __attribute__((ext_vector_type(8)));
typedef __bf16 bf16x8 __attribute__((ext_vector_type(8)));
typedef float f32x4 __attribute__((ext_vector_type(4)));

static __device__ __forceinline__ u16 f2bf(float f) {
  union { float f; uint32_t u; } v; v.f = f;
  uint32_t u = v.u;
  return (u16)((u + 0x7FFFu + ((u >> 16) & 1u)) >> 16);
}
static __device__ __forceinline__ float bf2f(u16 h) {
  union { uint32_t u; float f; } v; v.u = ((uint32_t)h) << 16;
  return v.f;
}

// ---------------- weight prep: BmatT[o][kk] = sum_c Wg[o,c]*Wt[c,i,k], kk=k*128+i
__global__ __launch_bounds__(384) void k_prepw(const float* __restrict__ Wt,
                                               const float* __restrict__ bt,
                                               const float* __restrict__ Wg,
                                               u16* __restrict__ BmatT,
                                               float* __restrict__ b2) {
  const int o = blockIdx.x;
  const int kk = threadIdx.x;          // 0..383
  const int k = kk >> 7, i = kk & 127;
  float acc = 0.f;
  for (int c = 0; c < CC; ++c)
    acc += Wg[o * CC + c] * Wt[(size_t)c * 384 + i * 3 + k];
  BmatT[(size_t)o * KKDIM + kk] = f2bf(acc);
  if (kk == 0) {
    float b = 0.f;
    for (int c = 0; c < CC; ++c) b += Wg[o * CC + c] * bt[c];
    b2[o] = b;
  }
}

// ---------------- degree / norm prep
__global__ __launch_bounds__(256) void k_deginit(float* __restrict__ deg) {
  int n = blockIdx.x * 256 + threadIdx.x;
  if (n < NN) deg[n] = 1.0f;  // self-loop weight
}
__global__ __launch_bounds__(256) void k_count(const int* __restrict__ ei,
                                               const float* __restrict__ ew,
                                               float* __restrict__ deg,
                                               int* __restrict__ cnt) {
  int e = blockIdx.x * 256 + threadIdx.x;
  if (e >= EE) return;
  int d = ei[EE + e];
  atomicAdd(&deg[d], ew[e]);
  atomicAdd(&cnt[d], 1);
}
__global__ __launch_bounds__(256) void k_dinv(float* __restrict__ deg) {
  int n = blockIdx.x * 256 + threadIdx.x;
  if (n >= NN) return;
  float d = deg[n];
  deg[n] = (d > 0.f) ? rsqrtf(fmaxf(d, 1e-12f)) : 0.f;
}

// ---------------- exclusive-scan (single block) -> rowptr
__global__ __launch_bounds__(1024) void k_scan(const int* __restrict__ cnt,
                                               int* __restrict__ rowptr) {
  __shared__ int part[1024];
  const int tid = threadIdx.x;
  const int base = tid * 20;
  int s = 0;
  for (int j = 0; j < 20; ++j) {
    int idx = base + j;
    if (idx < NN) s += cnt[idx];
  }
  part[tid] = s;
  __syncthreads();
  for (int off = 1; off < 1024; off <<= 1) {
    int u = 0;
    if (tid >= off) u = part[tid - off];
    __syncthreads();
    part[tid] += u;
    __syncthreads();
  }
  int run = part[tid] - s;  // exclusive prefix of this chunk
  for (int j = 0; j < 20; ++j) {
    int idx = base + j;
    if (idx < NN) { rowptr[idx] = run; run += cnt[idx]; }
  }
  if (tid == 1023) rowptr[NN] = part[1023];
}

__global__ __launch_bounds__(256) void k_scatter(const int* __restrict__ ei,
                                                 const float* __restrict__ ew,
                                                 const int* __restrict__ rowptr,
                                                 int* __restrict__ fill,
                                                 const float* __restrict__ dinv,
                                                 int* __restrict__ colb,
                                                 float* __restrict__ wnb) {
  int e = blockIdx.x * 256 + threadIdx.x;
  if (e >= EE) return;
  int s = ei[e], d = ei[EE + e];
  int pos = rowptr[d] + atomicAdd(&fill[d], 1);
  colb[pos] = s;
  wnb[pos] = dinv[s] * ew[e] * dinv[d];
}

// ---------------- fused temporal-conv + GCN-linear GEMM (bf16 MFMA)
// ht[t][n][o] = sum_{kk} A[n,kk] * BmatT[o,kk],  A[n,k*128+i]=x[t+k-1,n,i]
__global__ __launch_bounds__(256) void k_conv(const float* __restrict__ x,
                                              const u16* __restrict__ BmatT,
                                              const float* __restrict__ b2,
                                              u16* __restrict__ ht, int t0) {
  __shared__ __align__(16) u16 As[128][72];
  __shared__ __align__(16) u16 Bs[128][72];
  const int t = t0 + blockIdx.y;
  const int row0 = blockIdx.x * 128;
  u16* __restrict__ htT = ht + (size_t)blockIdx.y * (NN * CC);
  const int tid = threadIdx.x;
  const int lane = tid & 63;
  const int wv = tid >> 6;

  f32x4 acc[2][8];
  for (int m = 0; m < 2; ++m)
    for (int nb = 0; nb < 8; ++nb) acc[m][nb] = (f32x4){0.f, 0.f, 0.f, 0.f};

  const int r0 = tid >> 4;   // 0..15
  const int c4 = tid & 15;   // 0..15 -> 4 floats

  for (int kt = 0; kt < 6; ++kt) {
    const int kTap = kt >> 1;
    const int i0 = (kt & 1) * 64;
    const int tk = t + kTap - 1;
    const bool tkv = (tk >= 0) && (tk < TT);
    // stage A (f32 -> bf16 in regs -> LDS)
    #pragma unroll
    for (int j = 0; j < 8; ++j) {
      const int r = r0 + j * 16;
      const int grow = row0 + r;
      float4 v = make_float4(0.f, 0.f, 0.f, 0.f);
      if (tkv && grow < NN)
        v = *(const float4*)(x + ((size_t)tk * NN + grow) * CC + i0 + c4 * 4);
      u16x4 b;
      b[0] = f2bf(v.x); b[1] = f2bf(v.y); b[2] = f2bf(v.z); b[3] = f2bf(v.w);
      *(u16x4*)&As[r][c4 * 4] = b;
    }
    // stage B
    #pragma unroll
    for (int j = 0; j < 4; ++j) {
      const int idx = tid + j * 256;
      const int col = idx >> 3, q = idx & 7;
      *(u16x8*)&Bs[col][q * 8] =
          *(const u16x8*)(BmatT + (size_t)col * KKDIM + kt * 64 + q * 8);
    }
    __syncthreads();
    #pragma unroll
    for (int ks = 0; ks < 2; ++ks) {
      const int k0 = ks * 32 + ((lane >> 4) << 3);
      bf16x8 a0 = __builtin_bit_cast(bf16x8, *(const u16x8*)&As[wv * 32 + (lane & 15)][k0]);
      bf16x8 a1 = __builtin_bit_cast(bf16x8, *(const u16x8*)&As[wv * 32 + 16 + (lane & 15)][k0]);
      #pragma unroll
      for (int nb = 0; nb < 8; ++nb) {
        bf16x8 b = __builtin_bit_cast(bf16x8, *(const u16x8*)&Bs[nb * 16 + (lane & 15)][k0]);
        acc[0][nb] = __builtin_amdgcn_mfma_f32_16x16x32_bf16(a0, b, acc[0][nb], 0, 0, 0);
        acc[1][nb] = __builtin_amdgcn_mfma_f32_16x16x32_bf16(a1, b, acc[1][nb], 0, 0, 0);
      }
    }
    __syncthreads();
  }
  // epilogue: +b2, store bf16
  float b2v[8];
  #pragma unroll
  for (int nb = 0; nb < 8; ++nb) b2v[nb] = b2[nb * 16 + (lane & 15)];
  const int rb = row0 + wv * 32 + ((lane >> 4) << 2);
  #pragma unroll
  for (int m = 0; m < 2; ++m)
    #pragma unroll
    for (int nb = 0; nb < 8; ++nb)
      #pragma unroll
      for (int j = 0; j < 4; ++j) {
        const int r = rb + m * 16 + j;
        if (r < NN)
          htT[(size_t)r * CC + nb * 16 + (lane & 15)] = f2bf(acc[m][nb][j] + b2v[nb]);
      }
}

// ---------------- per-node CSR gather aggregation (one wave per node)
__global__ __launch_bounds__(256) void k_agg(const u16* __restrict__ ht,
                                             const int* __restrict__ colb,
                                             const float* __restrict__ wnb,
                                             const int* __restrict__ rowptr,
                                             const float* __restrict__ dinv,
                                             float* __restrict__ agg) {
  const int wv = threadIdx.x >> 6, lane = threadIdx.x & 63;
  const int n = blockIdx.x * 4 + wv;
  const u16* __restrict__ htT = ht + (size_t)blockIdx.y * (NN * CC);
  float* __restrict__ aggT = agg + (size_t)blockIdx.y * (NN * CC);
  const int c0 = lane * 2;
  const float dn = dinv[n];
  uint32_t v = *(const uint32_t*)(htT + (size_t)n * CC + c0);
  float a0 = bf2f((u16)(v & 0xFFFF)) * dn * dn;
  float a1 = bf2f((u16)(v >> 16)) * dn * dn;
  const int beg = rowptr[n], end = rowptr[n + 1];
  for (int p = beg; p < end; ++p) {
    int s = colb[p];
    float nw = wnb[p];
    uint32_t h = *(const uint32_t*)(htT + (size_t)s * CC + c0);
    a0 += bf2f((u16)(h & 0xFFFF)) * nw;
    a1 += bf2f((u16)(h >> 16)) * nw;
  }
  aggT[(size_t)n * CC + c0] = a0;
  aggT[(size_t)n * CC + c0 + 1] = a1;
}

// ---------------- BN stats (sum, sumsq per channel)
__global__ __launch_bounds__(256) void k_stats(const float* __restrict__ agg,
                                               float* __restrict__ stats, int t0) {
  const int t = t0 + blockIdx.y;
  const float* __restrict__ aggT = agg + (size_t)blockIdx.y * (NN * CC);
  const int tid = threadIdx.x;
  const int c = tid & 127, h = tid >> 7;
  const int nbeg = blockIdx.x * 625;
  float s = 0.f, q = 0.f;
  for (int n = nbeg + h; n < nbeg + 625; n += 2) {
    float v = aggT[(size_t)n * CC + c];
    s += v; q += v * v;
  }
  __shared__ float ls[256], lq[256];
  ls[tid] = s; lq[tid] = q;
  __syncthreads();
  if (tid < 128) {
    s = ls[tid] + ls[tid + 128];
    q = lq[tid] + lq[tid + 128];
    atomicAdd(&stats[t * 256 + c], s);
    atomicAdd(&stats[t * 256 + 128 + c], q);
  }
}

// ---------------- normalize + ReLU -> out
__global__ __launch_bounds__(256) void k_norm(const float* __restrict__ agg,
                                              const float* __restrict__ stats,
                                              const float* __restrict__ gamma,
                                              const float* __restrict__ beta,
                                              float* __restrict__ out, int t0) {
  const int t = t0 + blockIdx.y;
  const size_t base = (size_t)blockIdx.x * 1024 + threadIdx.x * 4;
  const float* __restrict__ aggT = agg + (size_t)blockIdx.y * (NN * CC);
  const int c = (int)(base & (CC - 1));
  float4 v = *(const float4*)(aggT + base);
  float4 su = *(const float4*)(stats + t * 256 + c);
  float4 sq = *(const float4*)(stats + t * 256 + 128 + c);
  float4 g = *(const float4*)(gamma + c);
  float4 bb = *(const float4*)(beta + c);
  const float inv_n = 1.f / (float)NN;
  float4 r;
  {
    float m = su.x * inv_n, var = sq.x * inv_n - m * m;
    r.x = fmaxf(g.x * (v.x - m) * rsqrtf(var + EPSV) + bb.x, 0.f);
  }
  {
    float m = su.y * inv_n, var = sq.y * inv_n - m * m;
    r.y = fmaxf(g.y * (v.y - m) * rsqrtf(var + EPSV) + bb.y, 0.f);
  }
  {
    float m = su.z * inv_n, var = sq.z * inv_n - m * m;
    r.z = fmaxf(g.z * (v.z - m) * rsqrtf(var + EPSV) + bb.z, 0.f);
  }
  {
    float m = su.w * inv_n, var = sq.w * inv_n - m * m;
    r.w = fmaxf(g.w * (v.w - m) * rsqrtf(var + EPSV) + bb.w, 0.f);
  }
  *(float4*)(out + (size_t)t * (NN * CC) + base) = r;
}

extern "C" void kernel_launch(void* const* d_in, const int* in_sizes, int n_in,
                              void* d_out, int out_size, void* d_ws, size_t ws_size,
                              hipStream_t stream) {
  const float* x     = (const float*)d_in[0];
  const int*   ei    = (const int*)d_in[1];
  const float* ew    = (const float*)d_in[2];
  const float* Wt    = (const float*)d_in[3];
  const float* bt    = (const float*)d_in[4];
  const float* Wg    = (const float*)d_in[5];
  // d_in[6] = bg: cancels exactly in BatchNorm -> unused
  const float* gamma = (const float*)d_in[7];
  const float* beta  = (const float*)d_in[8];
  float* out = (float*)d_out;
  char* ws = (char*)d_ws;

  // ws layout
  const size_t off_cnt    = 0;                       // 80000 (int)
  const size_t off_fill   = 80000;                   // 80000 (int)
  const size_t off_stats  = 160000;                  // 16*256*4 = 16384
  const size_t zero_bytes = 176384;                  // cnt|fill|stats contiguous
  const size_t off_deg    = 176384;                  // 80000 f32 (becomes dinv)
  const size_t off_rowptr = 256384;                  // 80004 -> pad to 336400
  const size_t off_colb   = 336400;                  // 1,280,000
  const size_t off_wnb    = 1616400;                 // 1,280,000
  const size_t off_BmatT  = 2896400;                 // 98,304
  const size_t off_b2     = 2994704;                 // 512
  const size_t off_ht     = 2995216;
  const size_t htA = (size_t)TT * NN * CC * 2;       // 81,920,000
  const size_t htB = (size_t)NN * CC * 2;            // 5,120,000
  const size_t aggA = (size_t)TT * NN * CC * 4;      // 163,840,000
  const size_t aggB = (size_t)NN * CC * 4;           // 10,240,000
  const size_t NEED_A = off_ht + htA + aggA;         // ~248.8 MB

  int*   cnt    = (int*)(ws + off_cnt);
  int*   fill   = (int*)(ws + off_fill);
  float* stats  = (float*)(ws + off_stats);
  float* deg    = (float*)(ws + off_deg);
  int*   rowptr = (int*)(ws + off_rowptr);
  int*   colb   = (int*)(ws + off_colb);
  float* wnb    = (float*)(ws + off_wnb);
  u16*   BmatT  = (u16*)(ws + off_BmatT);
  float* b2     = (float*)(ws + off_b2);

  const bool fused = (ws_size >= NEED_A);
  u16*   ht  = (u16*)(ws + off_ht);
  float* agg = (float*)(ws + off_ht + (fused ? htA : htB));

  hipMemsetAsync(ws, 0, zero_bytes, stream);
  k_prepw<<<dim3(CC), dim3(384), 0, stream>>>(Wt, bt, Wg, BmatT, b2);
  k_deginit<<<dim3((NN + 255) / 256), dim3(256), 0, stream>>>(deg);
  k_count<<<dim3((EE + 255) / 256), dim3(256), 0, stream>>>(ei, ew, deg, cnt);
  k_dinv<<<dim3((NN + 255) / 256), dim3(256), 0, stream>>>(deg);
  k_scan<<<dim3(1), dim3(1024), 0, stream>>>(cnt, rowptr);
  k_scatter<<<dim3((EE + 255) / 256), dim3(256), 0, stream>>>(ei, ew, rowptr, fill,
                                                              deg, colb, wnb);
  const int mtiles = (NN + 127) / 128;  // 157
  if (fused) {
    k_conv<<<dim3(mtiles, TT), dim3(256), 0, stream>>>(x, BmatT, b2, ht, 0);
    k_agg<<<dim3(NN / 4, TT), dim3(256), 0, stream>>>(ht, colb, wnb, rowptr, deg, agg);
    k_stats<<<dim3(32, TT), dim3(256), 0, stream>>>(agg, stats, 0);
    k_norm<<<dim3(NN * CC / 1024, TT), dim3(256), 0, stream>>>(agg, stats, gamma, beta, out, 0);
  } else {
    for (int t = 0; t < TT; ++t) {
      k_conv<<<dim3(mtiles, 1), dim3(256), 0, stream>>>(x, BmatT, b2, ht, t);
      k_agg<<<dim3(NN / 4, 1), dim3(256), 0, stream>>>(ht, colb, wnb, rowptr, deg, agg);
      k_stats<<<dim3(32, 1), dim3(256), 0, stream>>>(agg, stats, t);
      k_norm<<<dim3(NN * CC / 1024, 1), dim3(256), 0, stream>>>(agg, stats, gamma, beta, out, t);
    }
  }
}

// Round 2
// 546.042 us; speedup vs baseline: 1.6170x; 1.6170x over previous
//
#include <hip/hip_runtime.h>
#include <cstdint>

#define TT 16
#define NN 20000
#define CC 128
#define EE 320000
#define KKDIM 384
#define EPSV 1e-5f

typedef unsigned short u16;
typedef u16 u16x4 __attribute__((ext_vector_type(4)));
typedef u16 u16x8 __attribute__((ext_vector_type(8)));
typedef __bf16 bf16x8 __attribute__((ext_vector_type(8)));
typedef float f32x4 __attribute__((ext_vector_type(4)));

static __device__ __forceinline__ u16 f2bf(float f) {
  union { float f; uint32_t u; } v; v.f = f;
  uint32_t u = v.u;
  return (u16)((u + 0x7FFFu + ((u >> 16) & 1u)) >> 16);
}
static __device__ __forceinline__ float bf2f(u16 h) {
  union { uint32_t u; float f; } v; v.u = ((uint32_t)h) << 16;
  return v.f;
}

// ---------------- weight prep: BmatT[o][kk] = sum_c Wg[o,c]*Wt[c,i,k], kk=k*128+i
__global__ __launch_bounds__(384) void k_prepw(const float* __restrict__ Wt,
                                               const float* __restrict__ bt,
                                               const float* __restrict__ Wg,
                                               u16* __restrict__ BmatT,
                                               float* __restrict__ b2) {
  const int o = blockIdx.x;
  const int kk = threadIdx.x;          // 0..383
  const int k = kk >> 7, i = kk & 127;
  float acc = 0.f;
  for (int c = 0; c < CC; ++c)
    acc += Wg[o * CC + c] * Wt[(size_t)c * 384 + i * 3 + k];
  BmatT[(size_t)o * KKDIM + kk] = f2bf(acc);
  if (kk == 0) {
    float b = 0.f;
    for (int c = 0; c < CC; ++c) b += Wg[o * CC + c] * bt[c];
    b2[o] = b;
  }
}

// ---------------- degree / norm prep (self-loop folded in: deg=1, cnt=1)
__global__ __launch_bounds__(256) void k_deginit(float* __restrict__ deg,
                                                 int* __restrict__ cnt) {
  int n = blockIdx.x * 256 + threadIdx.x;
  if (n < NN) { deg[n] = 1.0f; cnt[n] = 1; }
}
__global__ __launch_bounds__(256) void k_count(const int* __restrict__ ei,
                                               const float* __restrict__ ew,
                                               float* __restrict__ deg,
                                               int* __restrict__ cnt) {
  int e = blockIdx.x * 256 + threadIdx.x;
  if (e >= EE) return;
  int d = ei[EE + e];
  atomicAdd(&deg[d], ew[e]);
  atomicAdd(&cnt[d], 1);
}
__global__ __launch_bounds__(256) void k_dinv(float* __restrict__ deg) {
  int n = blockIdx.x * 256 + threadIdx.x;
  if (n >= NN) return;
  float d = deg[n];
  deg[n] = (d > 0.f) ? rsqrtf(fmaxf(d, 1e-12f)) : 0.f;
}

// ---------------- exclusive-scan (single block) -> rowptr
__global__ __launch_bounds__(1024) void k_scan(const int* __restrict__ cnt,
                                               int* __restrict__ rowptr) {
  __shared__ int part[1024];
  const int tid = threadIdx.x;
  const int base = tid * 20;
  int s = 0;
  for (int j = 0; j < 20; ++j) {
    int idx = base + j;
    if (idx < NN) s += cnt[idx];
  }
  part[tid] = s;
  __syncthreads();
  for (int off = 1; off < 1024; off <<= 1) {
    int u = 0;
    if (tid >= off) u = part[tid - off];
    __syncthreads();
    part[tid] += u;
    __syncthreads();
  }
  int run = part[tid] - s;  // exclusive prefix of this chunk
  for (int j = 0; j < 20; ++j) {
    int idx = base + j;
    if (idx < NN) { rowptr[idx] = run; run += cnt[idx]; }
  }
  if (tid == 1023) rowptr[NN] = part[1023];
}

// ---------------- scatter edges + self-loops into packed CSR {col, w}
__global__ __launch_bounds__(256) void k_scatter(const int* __restrict__ ei,
                                                 const float* __restrict__ ew,
                                                 const int* __restrict__ rowptr,
                                                 int* __restrict__ fill,
                                                 const float* __restrict__ dinv,
                                                 int2* __restrict__ cw) {
  int e = blockIdx.x * 256 + threadIdx.x;
  if (e < EE) {
    int s = ei[e], d = ei[EE + e];
    int pos = rowptr[d] + atomicAdd(&fill[d], 1);
    cw[pos] = make_int2(s, __float_as_int(dinv[s] * ew[e] * dinv[d]));
  } else if (e < EE + NN) {
    int n = e - EE;
    float dn = dinv[n];
    int pos = rowptr[n] + atomicAdd(&fill[n], 1);
    cw[pos] = make_int2(n, __float_as_int(dn * dn));
  }
}

// ---------------- fused temporal-conv + GCN-linear GEMM (bf16 MFMA)
// ht layout: [n][t][c] bf16 -> elem (n,t,c) at n*2048 + t*128 + c
__global__ __launch_bounds__(256) void k_conv(const float* __restrict__ x,
                                              const u16* __restrict__ BmatT,
                                              const float* __restrict__ b2,
                                              u16* __restrict__ ht) {
  __shared__ __align__(16) u16 As[128][72];
  __shared__ __align__(16) u16 Bs[128][72];
  const int t = blockIdx.y;
  const int row0 = blockIdx.x * 128;
  const int tid = threadIdx.x;
  const int lane = tid & 63;
  const int wv = tid >> 6;

  f32x4 acc[2][8];
  for (int m = 0; m < 2; ++m)
    for (int nb = 0; nb < 8; ++nb) acc[m][nb] = (f32x4){0.f, 0.f, 0.f, 0.f};

  const int r0 = tid >> 4;   // 0..15
  const int c4 = tid & 15;   // 0..15 -> 4 floats

  for (int kt = 0; kt < 6; ++kt) {
    const int kTap = kt >> 1;
    const int i0 = (kt & 1) * 64;
    const int tk = t + kTap - 1;
    const bool tkv = (tk >= 0) && (tk < TT);
    // stage A (f32 -> bf16 in regs -> LDS)
    #pragma unroll
    for (int j = 0; j < 8; ++j) {
      const int r = r0 + j * 16;
      const int grow = row0 + r;
      float4 v = make_float4(0.f, 0.f, 0.f, 0.f);
      if (tkv && grow < NN)
        v = *(const float4*)(x + ((size_t)tk * NN + grow) * CC + i0 + c4 * 4);
      u16x4 b;
      b[0] = f2bf(v.x); b[1] = f2bf(v.y); b[2] = f2bf(v.z); b[3] = f2bf(v.w);
      *(u16x4*)&As[r][c4 * 4] = b;
    }
    // stage B
    #pragma unroll
    for (int j = 0; j < 4; ++j) {
      const int idx = tid + j * 256;
      const int col = idx >> 3, q = idx & 7;
      *(u16x8*)&Bs[col][q * 8] =
          *(const u16x8*)(BmatT + (size_t)col * KKDIM + kt * 64 + q * 8);
    }
    __syncthreads();
    #pragma unroll
    for (int ks = 0; ks < 2; ++ks) {
      const int k0 = ks * 32 + ((lane >> 4) << 3);
      bf16x8 a0 = __builtin_bit_cast(bf16x8, *(const u16x8*)&As[wv * 32 + (lane & 15)][k0]);
      bf16x8 a1 = __builtin_bit_cast(bf16x8, *(const u16x8*)&As[wv * 32 + 16 + (lane & 15)][k0]);
      #pragma unroll
      for (int nb = 0; nb < 8; ++nb) {
        bf16x8 b = __builtin_bit_cast(bf16x8, *(const u16x8*)&Bs[nb * 16 + (lane & 15)][k0]);
        acc[0][nb] = __builtin_amdgcn_mfma_f32_16x16x32_bf16(a0, b, acc[0][nb], 0, 0, 0);
        acc[1][nb] = __builtin_amdgcn_mfma_f32_16x16x32_bf16(a1, b, acc[1][nb], 0, 0, 0);
      }
    }
    __syncthreads();
  }
  // epilogue: +b2, store bf16 into [n][t][c]
  float b2v[8];
  #pragma unroll
  for (int nb = 0; nb < 8; ++nb) b2v[nb] = b2[nb * 16 + (lane & 15)];
  const int rb = row0 + wv * 32 + ((lane >> 4) << 2);
  #pragma unroll
  for (int m = 0; m < 2; ++m)
    #pragma unroll
    for (int nb = 0; nb < 8; ++nb)
      #pragma unroll
      for (int j = 0; j < 4; ++j) {
        const int r = rb + m * 16 + j;
        if (r < NN)
          ht[(size_t)r * 2048 + t * 128 + nb * 16 + (lane & 15)] =
              f2bf(acc[m][nb][j] + b2v[nb]);
      }
}

// ---------------- per-node CSR gather aggregation, all 16 t per block
// block = 256 thr = 4 waves; wave wv covers t in [wv*4, wv*4+4); lane covers 2 ch
__global__ __launch_bounds__(256) void k_agg(const u16* __restrict__ ht,
                                             const int2* __restrict__ cw,
                                             const int* __restrict__ rowptr,
                                             u16* __restrict__ agg) {
  const int n = blockIdx.x;
  const int tid = threadIdx.x;
  const int wv = tid >> 6, lane = tid & 63;
  const int tb = wv * 4;
  float a0[4] = {0.f, 0.f, 0.f, 0.f};
  float a1[4] = {0.f, 0.f, 0.f, 0.f};
  const int beg = rowptr[n], end = rowptr[n + 1];
  const int co = lane * 2;
  int p = beg;
  for (; p + 4 <= end; p += 4) {
    int2 e0 = cw[p], e1 = cw[p + 1], e2 = cw[p + 2], e3 = cw[p + 3];
    const u16* r0 = ht + (size_t)e0.x * 2048 + tb * 128 + co;
    const u16* r1 = ht + (size_t)e1.x * 2048 + tb * 128 + co;
    const u16* r2 = ht + (size_t)e2.x * 2048 + tb * 128 + co;
    const u16* r3 = ht + (size_t)e3.x * 2048 + tb * 128 + co;
    uint32_t v0[4], v1[4], v2[4], v3[4];
    #pragma unroll
    for (int j = 0; j < 4; ++j) v0[j] = *(const uint32_t*)(r0 + j * 128);
    #pragma unroll
    for (int j = 0; j < 4; ++j) v1[j] = *(const uint32_t*)(r1 + j * 128);
    #pragma unroll
    for (int j = 0; j < 4; ++j) v2[j] = *(const uint32_t*)(r2 + j * 128);
    #pragma unroll
    for (int j = 0; j < 4; ++j) v3[j] = *(const uint32_t*)(r3 + j * 128);
    const float w0 = __int_as_float(e0.y), w1 = __int_as_float(e1.y);
    const float w2 = __int_as_float(e2.y), w3 = __int_as_float(e3.y);
    #pragma unroll
    for (int j = 0; j < 4; ++j) {
      a0[j] = fmaf(bf2f((u16)(v0[j] & 0xFFFF)), w0, a0[j]);
      a1[j] = fmaf(bf2f((u16)(v0[j] >> 16)), w0, a1[j]);
      a0[j] = fmaf(bf2f((u16)(v1[j] & 0xFFFF)), w1, a0[j]);
      a1[j] = fmaf(bf2f((u16)(v1[j] >> 16)), w1, a1[j]);
      a0[j] = fmaf(bf2f((u16)(v2[j] & 0xFFFF)), w2, a0[j]);
      a1[j] = fmaf(bf2f((u16)(v2[j] >> 16)), w2, a1[j]);
      a0[j] = fmaf(bf2f((u16)(v3[j] & 0xFFFF)), w3, a0[j]);
      a1[j] = fmaf(bf2f((u16)(v3[j] >> 16)), w3, a1[j]);
    }
  }
  for (; p < end; ++p) {
    int2 e = cw[p];
    const u16* r = ht + (size_t)e.x * 2048 + tb * 128 + co;
    const float w = __int_as_float(e.y);
    #pragma unroll
    for (int j = 0; j < 4; ++j) {
      uint32_t v = *(const uint32_t*)(r + j * 128);
      a0[j] = fmaf(bf2f((u16)(v & 0xFFFF)), w, a0[j]);
      a1[j] = fmaf(bf2f((u16)(v >> 16)), w, a1[j]);
    }
  }
  u16* dst = agg + (size_t)n * 2048 + tb * 128 + co;
  #pragma unroll
  for (int j = 0; j < 4; ++j) {
    uint32_t pk = (uint32_t)f2bf(a0[j]) | ((uint32_t)f2bf(a1[j]) << 16);
    *(uint32_t*)(dst + j * 128) = pk;
  }
}

// ---------------- BN stats (sum, sumsq per (t,c)) from bf16 agg [n][t][c]
__global__ __launch_bounds__(256) void k_stats(const u16* __restrict__ agg,
                                               float* __restrict__ stats) {
  const int tid = threadIdx.x;
  const int c = tid & 127, th = tid >> 7;  // th in {0,1}
  float s[8], q[8];
  #pragma unroll
  for (int j = 0; j < 8; ++j) { s[j] = 0.f; q[j] = 0.f; }
  const int nbeg = blockIdx.x * 100, nend = nbeg + 100;
  for (int n = nbeg; n < nend; ++n) {
    const u16* row = agg + (size_t)n * 2048 + c;
    #pragma unroll
    for (int j = 0; j < 8; ++j) {
      float v = bf2f(row[(th * 8 + j) * 128]);
      s[j] += v; q[j] += v * v;
    }
  }
  #pragma unroll
  for (int j = 0; j < 8; ++j) {
    const int t = th * 8 + j;
    atomicAdd(&stats[t * 256 + c], s[j]);
    atomicAdd(&stats[t * 256 + 128 + c], q[j]);
  }
}

// ---------------- fold stats -> per-(t,c) scale/shift
__global__ __launch_bounds__(256) void k_fin(const float* __restrict__ stats,
                                             const float* __restrict__ gamma,
                                             const float* __restrict__ beta,
                                             float* __restrict__ scsh) {
  const int idx = blockIdx.x * 256 + threadIdx.x;  // 0..2047
  const int t = idx >> 7, c = idx & 127;
  const float inv_n = 1.f / (float)NN;
  float mu = stats[t * 256 + c] * inv_n;
  float var = stats[t * 256 + 128 + c] * inv_n - mu * mu;
  float sc = gamma[c] * rsqrtf(var + EPSV);
  scsh[t * 256 + c] = sc;
  scsh[t * 256 + 128 + c] = beta[c] - sc * mu;
}

// ---------------- normalize + ReLU: agg [n][t][c] bf16 -> out [t][n][c] f32
__global__ __launch_bounds__(256) void k_norm(const u16* __restrict__ agg,
                                              const float* __restrict__ scsh,
                                              float* __restrict__ out) {
  const int n = blockIdx.x;
  const int tid = threadIdx.x;
  const int c = tid & 127, th = tid >> 7;
  const u16* row = agg + (size_t)n * 2048 + c;
  #pragma unroll
  for (int j = 0; j < 8; ++j) {
    const int t = th * 8 + j;
    float v = bf2f(row[t * 128]);
    float sc = scsh[t * 256 + c];
    float sh = scsh[t * 256 + 128 + c];
    out[(size_t)t * (NN * CC) + (size_t)n * CC + c] = fmaxf(fmaf(v, sc, sh), 0.f);
  }
}

extern "C" void kernel_launch(void* const* d_in, const int* in_sizes, int n_in,
                              void* d_out, int out_size, void* d_ws, size_t ws_size,
                              hipStream_t stream) {
  const float* x     = (const float*)d_in[0];
  const int*   ei    = (const int*)d_in[1];
  const float* ew    = (const float*)d_in[2];
  const float* Wt    = (const float*)d_in[3];
  const float* bt    = (const float*)d_in[4];
  const float* Wg    = (const float*)d_in[5];
  // d_in[6] = bg: cancels exactly in BatchNorm -> unused
  const float* gamma = (const float*)d_in[7];
  const float* beta  = (const float*)d_in[8];
  float* out = (float*)d_out;
  char* ws = (char*)d_ws;

  // ws layout (bytes)
  const size_t off_cnt    = 0;           // NN*4 = 80000
  const size_t off_fill   = 80000;       // NN*4 = 80000
  const size_t off_stats  = 160000;      // 16*256*4 = 16384
  const size_t zero_bytes = 176384;      // cnt|fill|stats zeroed
  const size_t off_deg    = 176384;      // NN*4
  const size_t off_rowptr = 256384;      // (NN+1)*4 -> pad
  const size_t off_cw     = 336400;      // (E+N)*8 = 2,720,000
  const size_t off_BmatT  = 3056400;     // 128*384*2 = 98,304
  const size_t off_b2     = 3154704;     // 512
  const size_t off_scsh   = 3155216;     // 16*256*4 = 16,384
  const size_t off_ht     = 3171600;     // N*T*C*2 = 81,920,000
  const size_t off_agg    = 85091600;    // N*T*C*2 = 81,920,000 -> end ~167 MB

  int*   cnt    = (int*)(ws + off_cnt);
  int*   fill   = (int*)(ws + off_fill);
  float* stats  = (float*)(ws + off_stats);
  float* deg    = (float*)(ws + off_deg);
  int*   rowptr = (int*)(ws + off_rowptr);
  int2*  cw     = (int2*)(ws + off_cw);
  u16*   BmatT  = (u16*)(ws + off_BmatT);
  float* b2     = (float*)(ws + off_b2);
  float* scsh   = (float*)(ws + off_scsh);
  u16*   ht     = (u16*)(ws + off_ht);
  u16*   agg    = (u16*)(ws + off_agg);

  hipMemsetAsync(ws, 0, zero_bytes, stream);
  k_prepw<<<dim3(CC), dim3(384), 0, stream>>>(Wt, bt, Wg, BmatT, b2);
  k_deginit<<<dim3((NN + 255) / 256), dim3(256), 0, stream>>>(deg, cnt);
  k_count<<<dim3((EE + 255) / 256), dim3(256), 0, stream>>>(ei, ew, deg, cnt);
  k_dinv<<<dim3((NN + 255) / 256), dim3(256), 0, stream>>>(deg);
  k_scan<<<dim3(1), dim3(1024), 0, stream>>>(cnt, rowptr);
  k_scatter<<<dim3((EE + NN + 255) / 256), dim3(256), 0, stream>>>(ei, ew, rowptr,
                                                                   fill, deg, cw);
  const int mtiles = (NN + 127) / 128;  // 157
  k_conv<<<dim3(mtiles, TT), dim3(256), 0, stream>>>(x, BmatT, b2, ht);
  k_agg<<<dim3(NN), dim3(256), 0, stream>>>(ht, cw, rowptr, agg);
  k_stats<<<dim3(NN / 100), dim3(256), 0, stream>>>(agg, stats);
  k_fin<<<dim3(8), dim3(256), 0, stream>>>(stats, gamma, beta, scsh);
  k_norm<<<dim3(NN), dim3(256), 0, stream>>>(agg, scsh, out);
}

// Round 3
// 543.378 us; speedup vs baseline: 1.6249x; 1.0049x over previous
//
#include <hip/hip_runtime.h>
#include <cstdint>

#define TT 16
#define NN 20000
#define CC 128
#define EE 320000
#define KKDIM 384
#define EPSV 1e-5f

typedef unsigned short u16;
typedef u16 u16x4 __attribute__((ext_vector_type(4)));
typedef u16 u16x8 __attribute__((ext_vector_type(8)));
typedef __bf16 bf16x8 __attribute__((ext_vector_type(8)));
typedef float f32x4 __attribute__((ext_vector_type(4)));

static __device__ __forceinline__ u16 f2bf(float f) {
  union { float f; uint32_t u; } v; v.f = f;
  uint32_t u = v.u;
  return (u16)((u + 0x7FFFu + ((u >> 16) & 1u)) >> 16);
}
static __device__ __forceinline__ float bf2f(u16 h) {
  union { uint32_t u; float f; } v; v.u = ((uint32_t)h) << 16;
  return v.f;
}
// pack two f32 -> two bf16 (RNE) in one VALU op
static __device__ __forceinline__ uint32_t cvtpk(float lo, float hi) {
  uint32_t r;
  asm volatile("v_cvt_pk_bf16_f32 %0, %1, %2" : "=v"(r) : "v"(lo), "v"(hi));
  return r;
}

// ---------------- weight prep: BmatT[o][kk] = sum_c Wg[o,c]*Wt[c,i,k], kk=k*128+i
__global__ __launch_bounds__(384) void k_prepw(const float* __restrict__ Wt,
                                               const float* __restrict__ bt,
                                               const float* __restrict__ Wg,
                                               u16* __restrict__ BmatT,
                                               float* __restrict__ b2) {
  const int o = blockIdx.x;
  const int kk = threadIdx.x;          // 0..383
  const int k = kk >> 7, i = kk & 127;
  float acc = 0.f;
  for (int c = 0; c < CC; ++c)
    acc += Wg[o * CC + c] * Wt[(size_t)c * 384 + i * 3 + k];
  BmatT[(size_t)o * KKDIM + kk] = f2bf(acc);
  if (kk == 0) {
    float b = 0.f;
    for (int c = 0; c < CC; ++c) b += Wg[o * CC + c] * bt[c];
    b2[o] = b;
  }
}

// ---------------- degree / norm prep (self-loop folded in: deg=1, cnt=1)
__global__ __launch_bounds__(256) void k_deginit(float* __restrict__ deg,
                                                 int* __restrict__ cnt) {
  int n = blockIdx.x * 256 + threadIdx.x;
  if (n < NN) { deg[n] = 1.0f; cnt[n] = 1; }
}
__global__ __launch_bounds__(256) void k_count(const int* __restrict__ ei,
                                               const float* __restrict__ ew,
                                               float* __restrict__ deg,
                                               int* __restrict__ cnt) {
  int e = blockIdx.x * 256 + threadIdx.x;
  if (e >= EE) return;
  int d = ei[EE + e];
  atomicAdd(&deg[d], ew[e]);
  atomicAdd(&cnt[d], 1);
}
__global__ __launch_bounds__(256) void k_dinv(float* __restrict__ deg) {
  int n = blockIdx.x * 256 + threadIdx.x;
  if (n >= NN) return;
  float d = deg[n];
  deg[n] = (d > 0.f) ? rsqrtf(fmaxf(d, 1e-12f)) : 0.f;
}

// ---------------- exclusive-scan (single block) -> rowptr
__global__ __launch_bounds__(1024) void k_scan(const int* __restrict__ cnt,
                                               int* __restrict__ rowptr) {
  __shared__ int part[1024];
  const int tid = threadIdx.x;
  const int base = tid * 20;
  int s = 0;
  for (int j = 0; j < 20; ++j) {
    int idx = base + j;
    if (idx < NN) s += cnt[idx];
  }
  part[tid] = s;
  __syncthreads();
  for (int off = 1; off < 1024; off <<= 1) {
    int u = 0;
    if (tid >= off) u = part[tid - off];
    __syncthreads();
    part[tid] += u;
    __syncthreads();
  }
  int run = part[tid] - s;  // exclusive prefix of this chunk
  for (int j = 0; j < 20; ++j) {
    int idx = base + j;
    if (idx < NN) { rowptr[idx] = run; run += cnt[idx]; }
  }
  if (tid == 1023) rowptr[NN] = part[1023];
}

// ---------------- scatter edges + self-loops into packed CSR {col, w}
__global__ __launch_bounds__(256) void k_scatter(const int* __restrict__ ei,
                                                 const float* __restrict__ ew,
                                                 const int* __restrict__ rowptr,
                                                 int* __restrict__ fill,
                                                 const float* __restrict__ dinv,
                                                 int2* __restrict__ cw) {
  int e = blockIdx.x * 256 + threadIdx.x;
  if (e < EE) {
    int s = ei[e], d = ei[EE + e];
    int pos = rowptr[d] + atomicAdd(&fill[d], 1);
    cw[pos] = make_int2(s, __float_as_int(dinv[s] * ew[e] * dinv[d]));
  } else if (e < EE + NN) {
    int n = e - EE;
    float dn = dinv[n];
    int pos = rowptr[n] + atomicAdd(&fill[n], 1);
    cw[pos] = make_int2(n, __float_as_int(dn * dn));
  }
}

// ---------------- fused temporal-conv + GCN-linear GEMM (bf16 MFMA)
// ht layout: [n][t][c] bf16 -> elem (n,t,c) at n*2048 + t*128 + c
__global__ __launch_bounds__(256) void k_conv(const float* __restrict__ x,
                                              const u16* __restrict__ BmatT,
                                              const float* __restrict__ b2,
                                              u16* __restrict__ ht) {
  __shared__ __align__(16) u16 As[128][72];
  __shared__ __align__(16) u16 Bs[128][72];
  const int t = blockIdx.y;
  const int row0 = blockIdx.x * 128;
  const int tid = threadIdx.x;
  const int lane = tid & 63;
  const int wv = tid >> 6;

  f32x4 acc[2][8];
  for (int m = 0; m < 2; ++m)
    for (int nb = 0; nb < 8; ++nb) acc[m][nb] = (f32x4){0.f, 0.f, 0.f, 0.f};

  const int r0 = tid >> 4;   // 0..15
  const int c4 = tid & 15;   // 0..15 -> 4 floats

  for (int kt = 0; kt < 6; ++kt) {
    const int kTap = kt >> 1;
    const int i0 = (kt & 1) * 64;
    const int tk = t + kTap - 1;
    const bool tkv = (tk >= 0) && (tk < TT);
    // stage A (f32 -> bf16 via v_cvt_pk -> LDS)
    #pragma unroll
    for (int j = 0; j < 8; ++j) {
      const int r = r0 + j * 16;
      const int grow = row0 + r;
      float4 v = make_float4(0.f, 0.f, 0.f, 0.f);
      if (tkv && grow < NN)
        v = *(const float4*)(x + ((size_t)tk * NN + grow) * CC + i0 + c4 * 4);
      uint32_t pk0 = cvtpk(v.x, v.y);
      uint32_t pk1 = cvtpk(v.z, v.w);
      *(uint32_t*)&As[r][c4 * 4] = pk0;
      *(uint32_t*)&As[r][c4 * 4 + 2] = pk1;
    }
    // stage B
    #pragma unroll
    for (int j = 0; j < 4; ++j) {
      const int idx = tid + j * 256;
      const int col = idx >> 3, q = idx & 7;
      *(u16x8*)&Bs[col][q * 8] =
          *(const u16x8*)(BmatT + (size_t)col * KKDIM + kt * 64 + q * 8);
    }
    __syncthreads();
    #pragma unroll
    for (int ks = 0; ks < 2; ++ks) {
      const int k0 = ks * 32 + ((lane >> 4) << 3);
      bf16x8 a0 = __builtin_bit_cast(bf16x8, *(const u16x8*)&As[wv * 32 + (lane & 15)][k0]);
      bf16x8 a1 = __builtin_bit_cast(bf16x8, *(const u16x8*)&As[wv * 32 + 16 + (lane & 15)][k0]);
      #pragma unroll
      for (int nb = 0; nb < 8; ++nb) {
        bf16x8 b = __builtin_bit_cast(bf16x8, *(const u16x8*)&Bs[nb * 16 + (lane & 15)][k0]);
        acc[0][nb] = __builtin_amdgcn_mfma_f32_16x16x32_bf16(a0, b, acc[0][nb], 0, 0, 0);
        acc[1][nb] = __builtin_amdgcn_mfma_f32_16x16x32_bf16(a1, b, acc[1][nb], 0, 0, 0);
      }
    }
    __syncthreads();
  }
  // epilogue: +b2, store bf16 into [n][t][c]
  float b2v[8];
  #pragma unroll
  for (int nb = 0; nb < 8; ++nb) b2v[nb] = b2[nb * 16 + (lane & 15)];
  const int rb = row0 + wv * 32 + ((lane >> 4) << 2);
  #pragma unroll
  for (int m = 0; m < 2; ++m)
    #pragma unroll
    for (int nb = 0; nb < 8; ++nb)
      #pragma unroll
      for (int j = 0; j < 4; ++j) {
        const int r = rb + m * 16 + j;
        if (r < NN)
          ht[(size_t)r * 2048 + t * 128 + nb * 16 + (lane & 15)] =
              f2bf(acc[m][nb][j] + b2v[nb]);
      }
}

// ---------------- per-node CSR gather aggregation, all 16 t per block
// block = 256 thr = 4 waves; wave wv covers t in [wv*4, wv*4+4)
// lane covers 4 ch of plane tb+(lane>>5) via 8B loads spanning 2 planes (512B/wave)
__global__ __launch_bounds__(256) void k_agg(const u16* __restrict__ ht,
                                             const int2* __restrict__ cw,
                                             const int* __restrict__ rowptr,
                                             u16* __restrict__ agg) {
  const int n = blockIdx.x;
  const int tid = threadIdx.x;
  const int wv = tid >> 6, lane = tid & 63;
  const int tb = wv * 4;
  // elem offset within a node's 2048-elem [t][c] row:
  const int o0 = tb * 128 + lane * 4;        // planes tb, tb+1
  const int o1 = o0 + 256;                   // planes tb+2, tb+3
  float acc[2][4] = {{0.f,0.f,0.f,0.f},{0.f,0.f,0.f,0.f}};
  const int beg = rowptr[n], end = rowptr[n + 1];
  int p = beg;
  #define GATHER(ei_, vi_)                                              \
    {                                                                   \
      const u16* rr = ht + (size_t)(ei_).x * 2048;                      \
      vi_[0] = *(const u16x4*)(rr + o0);                                \
      vi_[1] = *(const u16x4*)(rr + o1);                                \
    }
  #define ACCUM(ei_, vi_)                                               \
    {                                                                   \
      const float w_ = __int_as_float((ei_).y);                         \
      _Pragma("unroll") for (int j = 0; j < 2; ++j)                     \
          _Pragma("unroll") for (int k = 0; k < 4; ++k)                 \
              acc[j][k] = fmaf(bf2f(vi_[j][k]), w_, acc[j][k]);         \
    }
  for (; p + 8 <= end; p += 8) {
    int2 e0 = cw[p],     e1 = cw[p + 1], e2 = cw[p + 2], e3 = cw[p + 3];
    int2 e4 = cw[p + 4], e5 = cw[p + 5], e6 = cw[p + 6], e7 = cw[p + 7];
    u16x4 v0[2], v1[2], v2[2], v3[2], v4[2], v5[2], v6[2], v7[2];
    GATHER(e0, v0) GATHER(e1, v1) GATHER(e2, v2) GATHER(e3, v3)
    GATHER(e4, v4) GATHER(e5, v5) GATHER(e6, v6) GATHER(e7, v7)
    ACCUM(e0, v0) ACCUM(e1, v1) ACCUM(e2, v2) ACCUM(e3, v3)
    ACCUM(e4, v4) ACCUM(e5, v5) ACCUM(e6, v6) ACCUM(e7, v7)
  }
  for (; p + 2 <= end; p += 2) {
    int2 e0 = cw[p], e1 = cw[p + 1];
    u16x4 v0[2], v1[2];
    GATHER(e0, v0) GATHER(e1, v1)
    ACCUM(e0, v0) ACCUM(e1, v1)
  }
  if (p < end) {
    int2 e0 = cw[p];
    u16x4 v0[2];
    GATHER(e0, v0)
    ACCUM(e0, v0)
  }
  #undef GATHER
  #undef ACCUM
  u16* dst = agg + (size_t)n * 2048;
  u16x4 s0, s1;
  #pragma unroll
  for (int k = 0; k < 4; ++k) { s0[k] = f2bf(acc[0][k]); s1[k] = f2bf(acc[1][k]); }
  *(u16x4*)(dst + o0) = s0;
  *(u16x4*)(dst + o1) = s1;
}

// ---------------- BN stats (sum, sumsq per (t,c)) from bf16 agg [n][t][c]
__global__ __launch_bounds__(256) void k_stats(const u16* __restrict__ agg,
                                               float* __restrict__ stats) {
  const int tid = threadIdx.x;
  const int c = tid & 127, th = tid >> 7;  // th in {0,1}
  float s[8], q[8];
  #pragma unroll
  for (int j = 0; j < 8; ++j) { s[j] = 0.f; q[j] = 0.f; }
  const int nbeg = blockIdx.x * 100, nend = nbeg + 100;
  for (int n = nbeg; n < nend; ++n) {
    const u16* row = agg + (size_t)n * 2048 + c;
    #pragma unroll
    for (int j = 0; j < 8; ++j) {
      float v = bf2f(row[(th * 8 + j) * 128]);
      s[j] += v; q[j] += v * v;
    }
  }
  #pragma unroll
  for (int j = 0; j < 8; ++j) {
    const int t = th * 8 + j;
    atomicAdd(&stats[t * 256 + c], s[j]);
    atomicAdd(&stats[t * 256 + 128 + c], q[j]);
  }
}

// ---------------- fold stats -> per-(t,c) scale/shift
__global__ __launch_bounds__(256) void k_fin(const float* __restrict__ stats,
                                             const float* __restrict__ gamma,
                                             const float* __restrict__ beta,
                                             float* __restrict__ scsh) {
  const int idx = blockIdx.x * 256 + threadIdx.x;  // 0..2047
  const int t = idx >> 7, c = idx & 127;
  const float inv_n = 1.f / (float)NN;
  float mu = stats[t * 256 + c] * inv_n;
  float var = stats[t * 256 + 128 + c] * inv_n - mu * mu;
  float sc = gamma[c] * rsqrtf(var + EPSV);
  scsh[t * 256 + c] = sc;
  scsh[t * 256 + 128 + c] = beta[c] - sc * mu;
}

// ---------------- normalize + ReLU: agg [n][t][c] bf16 -> out [t][n][c] f32
__global__ __launch_bounds__(256) void k_norm(const u16* __restrict__ agg,
                                              const float* __restrict__ scsh,
                                              float* __restrict__ out) {
  const int n = blockIdx.x;
  const int tid = threadIdx.x;
  const int c = tid & 127, th = tid >> 7;
  const u16* row = agg + (size_t)n * 2048 + c;
  #pragma unroll
  for (int j = 0; j < 8; ++j) {
    const int t = th * 8 + j;
    float v = bf2f(row[t * 128]);
    float sc = scsh[t * 256 + c];
    float sh = scsh[t * 256 + 128 + c];
    out[(size_t)t * (NN * CC) + (size_t)n * CC + c] = fmaxf(fmaf(v, sc, sh), 0.f);
  }
}

extern "C" void kernel_launch(void* const* d_in, const int* in_sizes, int n_in,
                              void* d_out, int out_size, void* d_ws, size_t ws_size,
                              hipStream_t stream) {
  const float* x     = (const float*)d_in[0];
  const int*   ei    = (const int*)d_in[1];
  const float* ew    = (const float*)d_in[2];
  const float* Wt    = (const float*)d_in[3];
  const float* bt    = (const float*)d_in[4];
  const float* Wg    = (const float*)d_in[5];
  // d_in[6] = bg: cancels exactly in BatchNorm -> unused
  const float* gamma = (const float*)d_in[7];
  const float* beta  = (const float*)d_in[8];
  float* out = (float*)d_out;
  char* ws = (char*)d_ws;

  // ws layout (bytes)
  const size_t off_cnt    = 0;           // NN*4 = 80000
  const size_t off_fill   = 80000;       // NN*4 = 80000
  const size_t off_stats  = 160000;      // 16*256*4 = 16384
  const size_t zero_bytes = 176384;      // cnt|fill|stats zeroed
  const size_t off_deg    = 176384;      // NN*4
  const size_t off_rowptr = 256384;      // (NN+1)*4 -> pad
  const size_t off_cw     = 336400;      // (E+N)*8 = 2,720,000
  const size_t off_BmatT  = 3056400;     // 128*384*2 = 98,304
  const size_t off_b2     = 3154704;     // 512
  const size_t off_scsh   = 3155216;     // 16*256*4 = 16,384
  const size_t off_ht     = 3171600;     // N*T*C*2 = 81,920,000
  const size_t off_agg    = 85091600;    // N*T*C*2 = 81,920,000 -> end ~167 MB

  int*   cnt    = (int*)(ws + off_cnt);
  int*   fill   = (int*)(ws + off_fill);
  float* stats  = (float*)(ws + off_stats);
  float* deg    = (float*)(ws + off_deg);
  int*   rowptr = (int*)(ws + off_rowptr);
  int2*  cw     = (int2*)(ws + off_cw);
  u16*   BmatT  = (u16*)(ws + off_BmatT);
  float* b2     = (float*)(ws + off_b2);
  float* scsh   = (float*)(ws + off_scsh);
  u16*   ht     = (u16*)(ws + off_ht);
  u16*   agg    = (u16*)(ws + off_agg);

  hipMemsetAsync(ws, 0, zero_bytes, stream);
  k_prepw<<<dim3(CC), dim3(384), 0, stream>>>(Wt, bt, Wg, BmatT, b2);
  k_deginit<<<dim3((NN + 255) / 256), dim3(256), 0, stream>>>(deg, cnt);
  k_count<<<dim3((EE + 255) / 256), dim3(256), 0, stream>>>(ei, ew, deg, cnt);
  k_dinv<<<dim3((NN + 255) / 256), dim3(256), 0, stream>>>(deg);
  k_scan<<<dim3(1), dim3(1024), 0, stream>>>(cnt, rowptr);
  k_scatter<<<dim3((EE + NN + 255) / 256), dim3(256), 0, stream>>>(ei, ew, rowptr,
                                                                   fill, deg, cw);
  const int mtiles = (NN + 127) / 128;  // 157
  k_conv<<<dim3(mtiles, TT), dim3(256), 0, stream>>>(x, BmatT, b2, ht);
  k_agg<<<dim3(NN), dim3(256), 0, stream>>>(ht, cw, rowptr, agg);
  k_stats<<<dim3(NN / 100), dim3(256), 0, stream>>>(agg, stats);
  k_fin<<<dim3(8), dim3(256), 0, stream>>>(stats, gamma, beta, scsh);
  k_norm<<<dim3(NN), dim3(256), 0, stream>>>(agg, scsh, out);
}

// Round 4
// 511.656 us; speedup vs baseline: 1.7256x; 1.0620x over previous
//
#include <hip/hip_runtime.h>
#include <cstdint>

#define TT 16
#define NN 20000
#define CC 128
#define EE 320000
#define KKDIM 384
#define EPSV 1e-5f

typedef unsigned short u16;
typedef u16 u16x4 __attribute__((ext_vector_type(4)));
typedef u16 u16x8 __attribute__((ext_vector_type(8)));
typedef __bf16 bf16x8 __attribute__((ext_vector_type(8)));
typedef float f32x4 __attribute__((ext_vector_type(4)));

static __device__ __forceinline__ u16 f2bf(float f) {
  union { float f; uint32_t u; } v; v.f = f;
  uint32_t u = v.u;
  return (u16)((u + 0x7FFFu + ((u >> 16) & 1u)) >> 16);
}
static __device__ __forceinline__ float bf2f(u16 h) {
  union { uint32_t u; float f; } v; v.u = ((uint32_t)h) << 16;
  return v.f;
}
// pack two f32 -> two bf16 (RNE) in one VALU op
static __device__ __forceinline__ uint32_t cvtpk(float lo, float hi) {
  uint32_t r;
  asm volatile("v_cvt_pk_bf16_f32 %0, %1, %2" : "=v"(r) : "v"(lo), "v"(hi));
  return r;
}

// ---------------- weight prep: BmatT[o][kk] = sum_c Wg[o,c]*Wt[c,i,k], kk=k*128+i
__global__ __launch_bounds__(384) void k_prepw(const float* __restrict__ Wt,
                                               const float* __restrict__ bt,
                                               const float* __restrict__ Wg,
                                               u16* __restrict__ BmatT,
                                               float* __restrict__ b2) {
  const int o = blockIdx.x;
  const int kk = threadIdx.x;          // 0..383
  const int k = kk >> 7, i = kk & 127;
  float acc = 0.f;
  for (int c = 0; c < CC; ++c)
    acc += Wg[o * CC + c] * Wt[(size_t)c * 384 + i * 3 + k];
  BmatT[(size_t)o * KKDIM + kk] = f2bf(acc);
  if (kk == 0) {
    float b = 0.f;
    for (int c = 0; c < CC; ++c) b += Wg[o * CC + c] * bt[c];
    b2[o] = b;
  }
}

// ---------------- degree / norm prep (self-loop folded in: deg=1, cnt=1)
__global__ __launch_bounds__(256) void k_deginit(float* __restrict__ deg,
                                                 int* __restrict__ cnt) {
  int n = blockIdx.x * 256 + threadIdx.x;
  if (n < NN) { deg[n] = 1.0f; cnt[n] = 1; }
}
__global__ __launch_bounds__(256) void k_count(const int* __restrict__ ei,
                                               const float* __restrict__ ew,
                                               float* __restrict__ deg,
                                               int* __restrict__ cnt) {
  int e = blockIdx.x * 256 + threadIdx.x;
  if (e >= EE) return;
  int d = ei[EE + e];
  atomicAdd(&deg[d], ew[e]);
  atomicAdd(&cnt[d], 1);
}
__global__ __launch_bounds__(256) void k_dinv(float* __restrict__ deg) {
  int n = blockIdx.x * 256 + threadIdx.x;
  if (n >= NN) return;
  float d = deg[n];
  deg[n] = (d > 0.f) ? rsqrtf(fmaxf(d, 1e-12f)) : 0.f;
}

// ---------------- exclusive-scan (single block) -> rowptr
__global__ __launch_bounds__(1024) void k_scan(const int* __restrict__ cnt,
                                               int* __restrict__ rowptr) {
  __shared__ int part[1024];
  const int tid = threadIdx.x;
  const int base = tid * 20;
  int s = 0;
  for (int j = 0; j < 20; ++j) {
    int idx = base + j;
    if (idx < NN) s += cnt[idx];
  }
  part[tid] = s;
  __syncthreads();
  for (int off = 1; off < 1024; off <<= 1) {
    int u = 0;
    if (tid >= off) u = part[tid - off];
    __syncthreads();
    part[tid] += u;
    __syncthreads();
  }
  int run = part[tid] - s;  // exclusive prefix of this chunk
  for (int j = 0; j < 20; ++j) {
    int idx = base + j;
    if (idx < NN) { rowptr[idx] = run; run += cnt[idx]; }
  }
  if (tid == 1023) rowptr[NN] = part[1023];
}

// ---------------- scatter edges + self-loops into packed CSR {col, w}
__global__ __launch_bounds__(256) void k_scatter(const int* __restrict__ ei,
                                                 const float* __restrict__ ew,
                                                 const int* __restrict__ rowptr,
                                                 int* __restrict__ fill,
                                                 const float* __restrict__ dinv,
                                                 int2* __restrict__ cw) {
  int e = blockIdx.x * 256 + threadIdx.x;
  if (e < EE) {
    int s = ei[e], d = ei[EE + e];
    int pos = rowptr[d] + atomicAdd(&fill[d], 1);
    cw[pos] = make_int2(s, __float_as_int(dinv[s] * ew[e] * dinv[d]));
  } else if (e < EE + NN) {
    int n = e - EE;
    float dn = dinv[n];
    int pos = rowptr[n] + atomicAdd(&fill[n], 1);
    cw[pos] = make_int2(n, __float_as_int(dn * dn));
  }
}

// ---------------- fused temporal-conv + GCN-linear GEMM (bf16 MFMA)
// ht layout: [n][t][c] bf16 -> elem (n,t,c) at n*2048 + t*128 + c
// grid: 2560 linear blocks; bid&7 -> XCD owns node tiles [xcd*20, xcd*20+20)
// for ALL t, so the 3x tap re-read of x hits that XCD's L2.
__global__ __launch_bounds__(256) void k_conv(const float* __restrict__ x,
                                              const u16* __restrict__ BmatT,
                                              const float* __restrict__ b2,
                                              u16* __restrict__ ht) {
  const int bid = blockIdx.x;
  const int xcd = bid & 7;
  const int s = bid >> 3;              // 0..319
  const int tile = xcd * 20 + (s % 20);
  const int t = s / 20;                // 0..15
  if (tile >= 157) return;
  __shared__ __align__(16) u16 As[128][72];
  __shared__ __align__(16) u16 Bs[128][72];
  const int row0 = tile * 128;
  const int tid = threadIdx.x;
  const int lane = tid & 63;
  const int wv = tid >> 6;

  f32x4 acc[2][8];
  for (int m = 0; m < 2; ++m)
    for (int nb = 0; nb < 8; ++nb) acc[m][nb] = (f32x4){0.f, 0.f, 0.f, 0.f};

  const int r0 = tid >> 4;   // 0..15
  const int c4 = tid & 15;   // 0..15 -> 4 floats

  for (int kt = 0; kt < 6; ++kt) {
    const int kTap = kt >> 1;
    const int i0 = (kt & 1) * 64;
    const int tk = t + kTap - 1;
    const bool tkv = (tk >= 0) && (tk < TT);
    // stage A (f32 -> bf16 via v_cvt_pk -> LDS)
    #pragma unroll
    for (int j = 0; j < 8; ++j) {
      const int r = r0 + j * 16;
      const int grow = row0 + r;
      float4 v = make_float4(0.f, 0.f, 0.f, 0.f);
      if (tkv && grow < NN)
        v = *(const float4*)(x + ((size_t)tk * NN + grow) * CC + i0 + c4 * 4);
      uint32_t pk0 = cvtpk(v.x, v.y);
      uint32_t pk1 = cvtpk(v.z, v.w);
      *(uint32_t*)&As[r][c4 * 4] = pk0;
      *(uint32_t*)&As[r][c4 * 4 + 2] = pk1;
    }
    // stage B
    #pragma unroll
    for (int j = 0; j < 4; ++j) {
      const int idx = tid + j * 256;
      const int col = idx >> 3, q = idx & 7;
      *(u16x8*)&Bs[col][q * 8] =
          *(const u16x8*)(BmatT + (size_t)col * KKDIM + kt * 64 + q * 8);
    }
    __syncthreads();
    #pragma unroll
    for (int ks = 0; ks < 2; ++ks) {
      const int k0 = ks * 32 + ((lane >> 4) << 3);
      bf16x8 a0 = __builtin_bit_cast(bf16x8, *(const u16x8*)&As[wv * 32 + (lane & 15)][k0]);
      bf16x8 a1 = __builtin_bit_cast(bf16x8, *(const u16x8*)&As[wv * 32 + 16 + (lane & 15)][k0]);
      #pragma unroll
      for (int nb = 0; nb < 8; ++nb) {
        bf16x8 b = __builtin_bit_cast(bf16x8, *(const u16x8*)&Bs[nb * 16 + (lane & 15)][k0]);
        acc[0][nb] = __builtin_amdgcn_mfma_f32_16x16x32_bf16(a0, b, acc[0][nb], 0, 0, 0);
        acc[1][nb] = __builtin_amdgcn_mfma_f32_16x16x32_bf16(a1, b, acc[1][nb], 0, 0, 0);
      }
    }
    __syncthreads();
  }
  // epilogue: +b2, store bf16 into [n][t][c]
  float b2v[8];
  #pragma unroll
  for (int nb = 0; nb < 8; ++nb) b2v[nb] = b2[nb * 16 + (lane & 15)];
  const int rb = row0 + wv * 32 + ((lane >> 4) << 2);
  #pragma unroll
  for (int m = 0; m < 2; ++m)
    #pragma unroll
    for (int nb = 0; nb < 8; ++nb)
      #pragma unroll
      for (int j = 0; j < 4; ++j) {
        const int r = rb + m * 16 + j;
        if (r < NN)
          ht[(size_t)r * 2048 + t * 128 + nb * 16 + (lane & 15)] =
              f2bf(acc[m][nb][j] + b2v[nb]);
      }
}

// ---------------- per-node CSR gather aggregation, XCD t-affinity split
// grid: 40000 blocks; tgroup = bid&7 (-> XCD); block covers 4 nodes (1/wave),
// each wave gathers 2 t-planes (512B/edge) => per-XCD distinct ht slice 10MB.
__global__ __launch_bounds__(256) void k_agg(const u16* __restrict__ ht,
                                             const int2* __restrict__ cw,
                                             const int* __restrict__ rowptr,
                                             u16* __restrict__ agg) {
  const int bid = blockIdx.x;
  const int tg = bid & 7;
  const int wv = threadIdx.x >> 6, lane = threadIdx.x & 63;
  const int n = (bid >> 3) * 4 + wv;
  const int o0 = tg * 256 + lane * 4;   // elems: planes {2tg, 2tg+1}
  float acc[4] = {0.f, 0.f, 0.f, 0.f};
  const int beg = rowptr[n], end = rowptr[n + 1];
  int p = beg;
  for (; p + 8 <= end; p += 8) {
    int2 e0 = cw[p],     e1 = cw[p + 1], e2 = cw[p + 2], e3 = cw[p + 3];
    int2 e4 = cw[p + 4], e5 = cw[p + 5], e6 = cw[p + 6], e7 = cw[p + 7];
    u16x4 v0 = *(const u16x4*)(ht + (size_t)e0.x * 2048 + o0);
    u16x4 v1 = *(const u16x4*)(ht + (size_t)e1.x * 2048 + o0);
    u16x4 v2 = *(const u16x4*)(ht + (size_t)e2.x * 2048 + o0);
    u16x4 v3 = *(const u16x4*)(ht + (size_t)e3.x * 2048 + o0);
    u16x4 v4 = *(const u16x4*)(ht + (size_t)e4.x * 2048 + o0);
    u16x4 v5 = *(const u16x4*)(ht + (size_t)e5.x * 2048 + o0);
    u16x4 v6 = *(const u16x4*)(ht + (size_t)e6.x * 2048 + o0);
    u16x4 v7 = *(const u16x4*)(ht + (size_t)e7.x * 2048 + o0);
    #define ACC1(e_, v_)                                              \
      {                                                               \
        const float w_ = __int_as_float((e_).y);                      \
        _Pragma("unroll") for (int k = 0; k < 4; ++k)                 \
            acc[k] = fmaf(bf2f((v_)[k]), w_, acc[k]);                 \
      }
    ACC1(e0, v0) ACC1(e1, v1) ACC1(e2, v2) ACC1(e3, v3)
    ACC1(e4, v4) ACC1(e5, v5) ACC1(e6, v6) ACC1(e7, v7)
  }
  for (; p < end; ++p) {
    int2 e = cw[p];
    u16x4 v = *(const u16x4*)(ht + (size_t)e.x * 2048 + o0);
    ACC1(e, v)
  }
  #undef ACC1
  u16x4 sv;
  #pragma unroll
  for (int k = 0; k < 4; ++k) sv[k] = f2bf(acc[k]);
  *(u16x4*)(agg + (size_t)n * 2048 + o0) = sv;
}

// ---------------- BN stats (sum, sumsq per (t,c)) from bf16 agg [n][t][c]
__global__ __launch_bounds__(256) void k_stats(const u16* __restrict__ agg,
                                               float* __restrict__ stats) {
  const int tid = threadIdx.x;
  const int c = tid & 127, th = tid >> 7;  // th in {0,1}
  float s[8], q[8];
  #pragma unroll
  for (int j = 0; j < 8; ++j) { s[j] = 0.f; q[j] = 0.f; }
  const int nbeg = blockIdx.x * 100, nend = nbeg + 100;
  for (int n = nbeg; n < nend; ++n) {
    const u16* row = agg + (size_t)n * 2048 + c;
    #pragma unroll
    for (int j = 0; j < 8; ++j) {
      float v = bf2f(row[(th * 8 + j) * 128]);
      s[j] += v; q[j] += v * v;
    }
  }
  #pragma unroll
  for (int j = 0; j < 8; ++j) {
    const int t = th * 8 + j;
    atomicAdd(&stats[t * 256 + c], s[j]);
    atomicAdd(&stats[t * 256 + 128 + c], q[j]);
  }
}

// ---------------- fold stats -> per-(t,c) scale/shift
__global__ __launch_bounds__(256) void k_fin(const float* __restrict__ stats,
                                             const float* __restrict__ gamma,
                                             const float* __restrict__ beta,
                                             float* __restrict__ scsh) {
  const int idx = blockIdx.x * 256 + threadIdx.x;  // 0..2047
  const int t = idx >> 7, c = idx & 127;
  const float inv_n = 1.f / (float)NN;
  float mu = stats[t * 256 + c] * inv_n;
  float var = stats[t * 256 + 128 + c] * inv_n - mu * mu;
  float sc = gamma[c] * rsqrtf(var + EPSV);
  scsh[t * 256 + c] = sc;
  scsh[t * 256 + 128 + c] = beta[c] - sc * mu;
}

// ---------------- normalize + ReLU: agg [n][t][c] bf16 -> out [t][n][c] f32
__global__ __launch_bounds__(256) void k_norm(const u16* __restrict__ agg,
                                              const float* __restrict__ scsh,
                                              float* __restrict__ out) {
  const int n = blockIdx.x;
  const int tid = threadIdx.x;
  const int c = tid & 127, th = tid >> 7;
  const u16* row = agg + (size_t)n * 2048 + c;
  #pragma unroll
  for (int j = 0; j < 8; ++j) {
    const int t = th * 8 + j;
    float v = bf2f(row[t * 128]);
    float sc = scsh[t * 256 + c];
    float sh = scsh[t * 256 + 128 + c];
    out[(size_t)t * (NN * CC) + (size_t)n * CC + c] = fmaxf(fmaf(v, sc, sh), 0.f);
  }
}

extern "C" void kernel_launch(void* const* d_in, const int* in_sizes, int n_in,
                              void* d_out, int out_size, void* d_ws, size_t ws_size,
                              hipStream_t stream) {
  const float* x     = (const float*)d_in[0];
  const int*   ei    = (const int*)d_in[1];
  const float* ew    = (const float*)d_in[2];
  const float* Wt    = (const float*)d_in[3];
  const float* bt    = (const float*)d_in[4];
  const float* Wg    = (const float*)d_in[5];
  // d_in[6] = bg: cancels exactly in BatchNorm -> unused
  const float* gamma = (const float*)d_in[7];
  const float* beta  = (const float*)d_in[8];
  float* out = (float*)d_out;
  char* ws = (char*)d_ws;

  // ws layout (bytes)
  const size_t off_cnt    = 0;           // NN*4 = 80000
  const size_t off_fill   = 80000;       // NN*4 = 80000
  const size_t off_stats  = 160000;      // 16*256*4 = 16384
  const size_t zero_bytes = 176384;      // cnt|fill|stats zeroed
  const size_t off_deg    = 176384;      // NN*4
  const size_t off_rowptr = 256384;      // (NN+1)*4 -> pad
  const size_t off_cw     = 336400;      // (E+N)*8 = 2,720,000
  const size_t off_BmatT  = 3056400;     // 128*384*2 = 98,304
  const size_t off_b2     = 3154704;     // 512
  const size_t off_scsh   = 3155216;     // 16*256*4 = 16,384
  const size_t off_ht     = 3171600;     // N*T*C*2 = 81,920,000
  const size_t off_agg    = 85091600;    // N*T*C*2 = 81,920,000 -> end ~167 MB

  int*   cnt    = (int*)(ws + off_cnt);
  int*   fill   = (int*)(ws + off_fill);
  float* stats  = (float*)(ws + off_stats);
  float* deg    = (float*)(ws + off_deg);
  int*   rowptr = (int*)(ws + off_rowptr);
  int2*  cw     = (int2*)(ws + off_cw);
  u16*   BmatT  = (u16*)(ws + off_BmatT);
  float* b2     = (float*)(ws + off_b2);
  float* scsh   = (float*)(ws + off_scsh);
  u16*   ht     = (u16*)(ws + off_ht);
  u16*   agg    = (u16*)(ws + off_agg);

  hipMemsetAsync(ws, 0, zero_bytes, stream);
  k_prepw<<<dim3(CC), dim3(384), 0, stream>>>(Wt, bt, Wg, BmatT, b2);
  k_deginit<<<dim3((NN + 255) / 256), dim3(256), 0, stream>>>(deg, cnt);
  k_count<<<dim3((EE + 255) / 256), dim3(256), 0, stream>>>(ei, ew, deg, cnt);
  k_dinv<<<dim3((NN + 255) / 256), dim3(256), 0, stream>>>(deg);
  k_scan<<<dim3(1), dim3(1024), 0, stream>>>(cnt, rowptr);
  k_scatter<<<dim3((EE + NN + 255) / 256), dim3(256), 0, stream>>>(ei, ew, rowptr,
                                                                   fill, deg, cw);
  k_conv<<<dim3(2560), dim3(256), 0, stream>>>(x, BmatT, b2, ht);
  k_agg<<<dim3(40000), dim3(256), 0, stream>>>(ht, cw, rowptr, agg);
  k_stats<<<dim3(NN / 100), dim3(256), 0, stream>>>(agg, stats);
  k_fin<<<dim3(8), dim3(256), 0, stream>>>(stats, gamma, beta, scsh);
  k_norm<<<dim3(NN), dim3(256), 0, stream>>>(agg, scsh, out);
}